// Round 3
// baseline (296.423 us; speedup 1.0000x reference)
//
#include <hip/hip_runtime.h>

// Problem constants (from reference setup_inputs)
#define BATCH 256
#define IMG_H 240
#define IMG_W 320
#define NCH   3
#define PSZ   128

// One thread per output element (B*P*P). Each 256-thread block is fully
// inside one batch (P*P = 16384 = 64 blocks of 256).
__global__ __launch_bounds__(256)
void ImageTransformer_36490042147683_kernel(
    const float* __restrict__ I,     // f32, (B,H,W,C)
    const float* __restrict__ Hm,    // f32, (B,3,3)
    const float* __restrict__ Mm,    // f32, (3,3)   (M)
    const float* __restrict__ Mi,    // f32, (3,3)   (M_inv)
    const int*   __restrict__ pidx,  // int32, (B,P,P)
    const int*   __restrict__ boff,  // int32, (B,)
    float*       __restrict__ out)   // f32, (B,P,P,1)
{
    __shared__ float Hs[9];      // H_eff for this block's batch
    __shared__ int   base_s;     // batch_offsets[b]

    const int b = blockIdx.x >> 6;   // 64 blocks per batch

    if (threadIdx.x == 0) {
        float hm[9], m[9], mi[9], t[9];
        #pragma unroll
        for (int k = 0; k < 9; ++k) {
            hm[k] = Hm[b * 9 + k];
            m[k]  = Mm[k];
            mi[k] = Mi[k];
        }
        // t = H_mat @ M ; H_eff = M_inv @ t
        #pragma unroll
        for (int i = 0; i < 3; ++i)
            #pragma unroll
            for (int j = 0; j < 3; ++j)
                t[i*3+j] = hm[i*3+0]*m[0*3+j] + hm[i*3+1]*m[1*3+j] + hm[i*3+2]*m[2*3+j];
        #pragma unroll
        for (int i = 0; i < 3; ++i)
            #pragma unroll
            for (int j = 0; j < 3; ++j)
                Hs[i*3+j] = mi[i*3+0]*t[0*3+j] + mi[i*3+1]*t[1*3+j] + mi[i*3+2]*t[2*3+j];
        base_s = boff[b];
    }
    __syncthreads();

    const int gid = blockIdx.x * 256 + threadIdx.x;   // output flat index
    const int idx = pidx[gid];                        // within-image pixel index
    const int y   = idx / IMG_W;
    const int x   = idx - y * IMG_W;

    // linspace(-1,1,N)[k] = -1 + k * 2/(N-1)
    const float gx = fmaf((float)x, 2.0f / (IMG_W - 1), -1.0f);
    const float gy = fmaf((float)y, 2.0f / (IMG_H - 1), -1.0f);

    const float t0 = Hs[0] * gx + Hs[1] * gy + Hs[2];
    const float t1 = Hs[3] * gx + Hs[4] * gy + Hs[5];
    const float t2 = Hs[6] * gx + Hs[7] * gy + Hs[8];

    const float denom = (fabsf(t2) < 1e-7f) ? 1e-7f : t2;

    const float xs = (t0 / denom + 1.0f) * (IMG_W * 0.5f);
    const float ys = (t1 / denom + 1.0f) * (IMG_H * 0.5f);

    const float xf = floorf(xs);
    const float yf = floorf(ys);

    int x0 = (int)xf;       // v_cvt_i32_f32 saturates like jnp astype on GPU
    int y0 = (int)yf;
    int x1 = x0 + 1;
    int y1 = y0 + 1;
    x0 = min(max(x0, 0), IMG_W - 1);
    x1 = min(max(x1, 0), IMG_W - 1);
    y0 = min(max(y0, 0), IMG_H - 1);
    y1 = min(max(y1, 0), IMG_H - 1);

    // Weights use CLIPPED coords, matching the reference exactly.
    const float x0f = (float)x0, x1f = (float)x1;
    const float y0f = (float)y0, y1f = (float)y1;
    const float wa = (x1f - xs) * (y1f - ys);
    const float wb = (x1f - xs) * (ys - y0f);
    const float wc = (xs - x0f) * (y1f - ys);
    const float wd = (xs - x0f) * (ys - y0f);

    // gray(corner) = mean over channels; mean is linear so blending grays
    // equals channel-wise blend then mean.
    const float* img = I + (size_t)base_s * NCH;

    const float* pa = img + (size_t)(y0 * IMG_W + x0) * NCH;
    const float* pb = img + (size_t)(y1 * IMG_W + x0) * NCH;
    const float* pc = img + (size_t)(y0 * IMG_W + x1) * NCH;
    const float* pd = img + (size_t)(y1 * IMG_W + x1) * NCH;

    const float ga = (pa[0] + pa[1] + pa[2]) * (1.0f / 3.0f);
    const float gb = (pb[0] + pb[1] + pb[2]) * (1.0f / 3.0f);
    const float gc = (pc[0] + pc[1] + pc[2]) * (1.0f / 3.0f);
    const float gd = (pd[0] + pd[1] + pd[2]) * (1.0f / 3.0f);

    const float g = wa * ga + wb * gb + wc * gc + wd * gd;

    out[gid] = g;
}

extern "C" void kernel_launch(void* const* d_in, const int* in_sizes, int n_in,
                              void* d_out, int out_size, void* d_ws, size_t ws_size,
                              hipStream_t stream) {
    const float* I    = (const float*)d_in[0];
    const float* Hm   = (const float*)d_in[1];
    const float* Mm   = (const float*)d_in[2];  // M
    const float* Mi   = (const float*)d_in[3];  // M_inv
    const int*   pidx = (const int*)d_in[4];
    const int*   boff = (const int*)d_in[5];
    float*       out  = (float*)d_out;

    const int total  = BATCH * PSZ * PSZ;     // 4,194,304
    const int blocks = total / 256;           // 16,384

    ImageTransformer_36490042147683_kernel<<<blocks, 256, 0, stream>>>(
        I, Hm, Mm, Mi, pidx, boff, out);
}